// Round 5
// baseline (772.063 us; speedup 1.0000x reference)
//
#include <hip/hip_runtime.h>
#include <stdint.h>

typedef __attribute__((ext_vector_type(8))) short short8;
typedef __attribute__((ext_vector_type(4))) float f32x4;

__device__ __forceinline__ unsigned short f2bf(float x) {
  unsigned int u = __float_as_uint(x);
  u += 0x7fffu + ((u >> 16) & 1u);
  return (unsigned short)(u >> 16);
}
__device__ __forceinline__ float bf2f(unsigned short h) {
  return __uint_as_float(((unsigned int)h) << 16);
}

#define GLOAD16(gsrc, ldst)                                              \
  __builtin_amdgcn_global_load_lds(                                      \
      (const __attribute__((address_space(1))) void*)(gsrc),             \
      (__attribute__((address_space(3))) void*)(ldst), 16, 0, 0)

// ---------- split fp32 -> (hi, lo) bf16 ----------
__global__ __launch_bounds__(256) void split_pair_kernel(
    const float* __restrict__ in, unsigned short* __restrict__ h,
    unsigned short* __restrict__ l) {
  size_t i = (size_t)blockIdx.x * 256 + threadIdx.x;
  float4 v = ((const float4*)in)[i];
  unsigned short h0 = f2bf(v.x), h1 = f2bf(v.y), h2 = f2bf(v.z), h3 = f2bf(v.w);
  ((ushort4*)h)[i] = make_ushort4(h0, h1, h2, h3);
  ((ushort4*)l)[i] = make_ushort4(f2bf(v.x - bf2f(h0)), f2bf(v.y - bf2f(h1)),
                                  f2bf(v.z - bf2f(h2)), f2bf(v.w - bf2f(h3)));
}

// ---------- transpose W [K][N] fp32 -> hi/lo bf16 [N][K] ----------
__global__ __launch_bounds__(256) void transpose_split_kernel(
    const float* __restrict__ W, unsigned short* __restrict__ hT,
    unsigned short* __restrict__ lT, int Kd, int Nd) {
  __shared__ float tile[32][33];
  int r = threadIdx.x >> 3;
  int c = (threadIdx.x & 7) * 4;
  int k0 = blockIdx.y * 32, n0 = blockIdx.x * 32;
  float4 v = *(const float4*)&W[(size_t)(k0 + r) * Nd + n0 + c];
  tile[r][c] = v.x; tile[r][c + 1] = v.y; tile[r][c + 2] = v.z; tile[r][c + 3] = v.w;
  __syncthreads();
  float x0 = tile[c + 0][r], x1 = tile[c + 1][r], x2 = tile[c + 2][r], x3 = tile[c + 3][r];
  unsigned short h0 = f2bf(x0), h1 = f2bf(x1), h2 = f2bf(x2), h3 = f2bf(x3);
  size_t o = (size_t)(n0 + r) * Kd + k0 + c;
  *(ushort4*)&hT[o] = make_ushort4(h0, h1, h2, h3);
  *(ushort4*)&lT[o] = make_ushort4(f2bf(x0 - bf2f(h0)), f2bf(x1 - bf2f(h1)),
                                   f2bf(x2 - bf2f(h2)), f2bf(x3 - bf2f(h3)));
}

// =====================================================================
// 8-phase 256x256 BK=64 bf16 NT GEMM, K-segmented operands.
// Half-tiles grouped by QUADRANT USAGE:
//   HA0 = A rowgroups {0-3,8-11}   read ph0 (regs persist through ph1)
//   HA1 = A rowgroups {4-7,12-15}  read ph2 (persist ph3)
//   HB0 = B rowgroups {0,1,4,5,8,9,12,13}  read ph0,ph2
//   HB1 = B rowgroups {2,3,6,7,10,11,14,15} read ph1,ph3
// Staging order matches consumption order (FIFO-friendly):
//   ph0 HB1(t+1)->nbuf, ph1 HA1(t+1)->nbuf, ph2 HA0(t+2)->buf, ph3 HB0(t+2)->buf
// Waits: VM(8) at ph0/ph1/ph3 only (each drains loads issued >=4 phases
// earlier = a full K-tile of latency budget); ph2 has no vmem wait.
// Tails: (st1,!st2): ph3 VM(4); last tile: ph0 VM(2), ph1 VM(0).
// LDS 128KB = 2buf x (A 32KB + B 32KB), subtile 16rows x 32k = 1KB,
// fragment-linear (lane l owns bytes [16l,16l+16)).
// Grid convention: gridDim.x = M-blocks (fastest), gridDim.y = N-blocks;
// XCD-bijective swizzle (nwg % 8 == 0 in all launches) -> per-XCD chunk
// shares a small B-panel (L2-resident), A streams from L3.
// =====================================================================
#define LDA4(BUF, QR)                                                        \
  _Pragma("unroll") for (int _i = 0; _i < 4; ++_i)                           \
  _Pragma("unroll") for (int _k = 0; _k < 2; ++_k)                           \
      areg[_i][_k] = *(const short8*)(smem + (BUF) * 65536 +                 \
          ((wm * 8 + (QR) * 4 + _i) * 2 + _k) * 1024 + lane * 16);

#define LDB2(BUF, QC)                                                        \
  _Pragma("unroll") for (int _j = 0; _j < 2; ++_j)                           \
  _Pragma("unroll") for (int _k = 0; _k < 2; ++_k)                           \
      breg[_j][_k] = *(const short8*)(smem + (BUF) * 65536 + 32768 +         \
          ((wn * 4 + (QC) * 2 + _j) * 2 + _k) * 1024 + lane * 16);

#define MMA16(QR, QC)                                                        \
  __builtin_amdgcn_s_setprio(1);                                             \
  _Pragma("unroll") for (int _i = 0; _i < 4; ++_i)                           \
  _Pragma("unroll") for (int _j = 0; _j < 2; ++_j)                           \
  _Pragma("unroll") for (int _k = 0; _k < 2; ++_k)                           \
      acc[(QR) * 4 + _i][(QC) * 2 + _j] =                                    \
          __builtin_amdgcn_mfma_f32_16x16x32_bf16(                           \
              areg[_i][_k], breg[_j][_k], acc[(QR) * 4 + _i][(QC) * 2 + _j], \
              0, 0, 0);                                                      \
  __builtin_amdgcn_s_setprio(0);

__device__ __forceinline__ const unsigned short* segsel(
    const unsigned short* s0, const unsigned short* s1,
    const unsigned short* s2, const unsigned short* s3, int seg) {
  return seg == 0 ? s0 : seg == 1 ? s1 : seg == 2 ? s2 : s3;
}

// HALF: 0=HA0, 1=HA1, 2=HB0, 3=HB1. 2 gloads (k-halves of one rowgroup).
#define STAGE(BUF, HALF, KT)                                                 \
  {                                                                          \
    const int _seg = (KT) >> 4;                                              \
    const int _ko = ((KT) & 15) * 64;                                        \
    const unsigned short* _sb = ((HALF) < 2)                                 \
        ? segsel(A0, A1, A2, A3, _seg) : segsel(B0, B1, B2, B3, _seg);       \
    const size_t _src = (((HALF) < 2) ? rowOffA[(HALF)] : rowOffB[(HALF)-2]) \
        + (size_t)_ko;                                                       \
    char* _d = smem + (BUF) * 65536 +                                        \
        (((HALF) < 2) ? dstA[(HALF)] : dstB[(HALF)-2]);                      \
    GLOAD16(_sb + _src, _d);                                                 \
    GLOAD16(_sb + _src + 32, _d + 1024);                                     \
  }

#define VM(N) asm volatile("s_waitcnt vmcnt(" #N ")" ::: "memory")
#define BARSYNC __builtin_amdgcn_s_barrier()
#define LGKM0                                                \
  do {                                                       \
    asm volatile("s_waitcnt lgkmcnt(0)" ::: "memory");       \
    __builtin_amdgcn_sched_barrier(0);                       \
  } while (0)

template <int OM>  // 0: fp32 out; 3: fused QKV epilogue
__global__ __launch_bounds__(512, 2) void g8_kernel(
    const unsigned short* A0, const unsigned short* A1,
    const unsigned short* A2, const unsigned short* A3,
    const unsigned short* B0, const unsigned short* B1,
    const unsigned short* B2, const unsigned short* B3,
    int K, int lda, int ldb, float* outF, int ldo,
    const float* bq, const float* bk, const float* bv,
    unsigned short* qh, unsigned short* ql, unsigned short* kh,
    unsigned short* kl, unsigned short* vT) {
  __shared__ __attribute__((aligned(16))) char smem[131072];
  const int t = threadIdx.x, wid = t >> 6, lane = t & 63;
  const int wm = wid >> 2, wn = wid & 3;
  const int lr = lane & 15, lk0 = (lane >> 4) * 8;

  // XCD-bijective swizzle: dispatch index d -> work item (d&7)*cpx + d>>3.
  // gridDim.x = M-blocks (fastest in both dispatch and work order).
  const int nwg = gridDim.x * gridDim.y;
  int bid = blockIdx.y * gridDim.x + blockIdx.x;
  bid = (bid & 7) * (nwg >> 3) + (bid >> 3);
  const int m0 = (bid % gridDim.x) * 256;
  const int n0 = (bid / gridDim.x) * 256;

  // per-wave staging rowgroups for each half-tile
  const int rgA0 = wid + ((wid >> 2) << 2);            // {0-3,8-11}
  const int rgA1 = 4 + rgA0;                           // {4-7,12-15}
  const int rgB0 = (wid & 1) + ((wid >> 1) << 2);      // {0,1,4,5,8,9,12,13}
  const int rgB1 = 2 + rgB0;                           // {2,3,6,7,10,11,14,15}
  size_t rowOffA[2] = {(size_t)(m0 + rgA0 * 16 + lr) * lda + lk0,
                       (size_t)(m0 + rgA1 * 16 + lr) * lda + lk0};
  size_t rowOffB[2] = {(size_t)(n0 + rgB0 * 16 + lr) * ldb + lk0,
                       (size_t)(n0 + rgB1 * 16 + lr) * ldb + lk0};
  const int dstA[2] = {rgA0 * 2048, rgA1 * 2048};
  const int dstB[2] = {32768 + rgB0 * 2048, 32768 + rgB1 * 2048};

  const int NT = K >> 6;
  f32x4 acc[8][4] = {};
  short8 areg[4][2], breg[2][2];

  // prologue (FIFO ordering consistent with steady state):
  // HA0(0), HB0(0), HB1(0), HA1(0), HA0(1), HB0(1); land first 2 pairs.
  STAGE(0, 0, 0);
  STAGE(0, 2, 0);
  STAGE(0, 3, 0);
  STAGE(0, 1, 0);
  STAGE(1, 0, 1);
  STAGE(1, 2, 1);
  VM(8);
  BARSYNC;

#pragma unroll 1
  for (int tt = 0; tt < NT; ++tt) {
    const int buf = tt & 1, nbuf = buf ^ 1;
    const bool st1 = (tt + 1 < NT), st2 = (tt + 2 < NT);
    // ---- phase 0: quad(0,0); stage HB1(t+1)
    LDA4(buf, 0) LDB2(buf, 0)
    if (st1) STAGE(nbuf, 3, tt + 1);
    BARSYNC; LGKM0;
    MMA16(0, 0)
    if (st1) { VM(8); } else { VM(2); }
    BARSYNC;
    // ---- phase 1: quad(0,1); stage HA1(t+1)
    LDB2(buf, 1)
    if (st1) STAGE(nbuf, 1, tt + 1);
    BARSYNC; LGKM0;
    MMA16(0, 1)
    if (st1) { VM(8); } else { VM(0); }
    BARSYNC;
    // ---- phase 2: quad(1,0); stage HA0(t+2); no vmem wait needed
    LDA4(buf, 1) LDB2(buf, 0)
    if (st2) STAGE(buf, 0, tt + 2);
    BARSYNC; LGKM0;
    MMA16(1, 0)
    BARSYNC;
    // ---- phase 3: quad(1,1); stage HB0(t+2)
    LDB2(buf, 1)
    if (st2) STAGE(buf, 2, tt + 2);
    BARSYNC; LGKM0;
    MMA16(1, 1)
    if (st2) { VM(8); } else if (st1) { VM(4); }
    BARSYNC;
  }

  // epilogue: C/D frag layout col=lane&15, row=(lane>>4)*4+r
  const int or0 = (lane >> 4) * 4;
  if constexpr (OM == 0) {
#pragma unroll
    for (int rg = 0; rg < 8; ++rg)
#pragma unroll
      for (int cg = 0; cg < 4; ++cg)
#pragma unroll
        for (int r = 0; r < 4; ++r)
          outF[(size_t)(m0 + wm * 128 + rg * 16 + or0 + r) * ldo +
               (n0 + wn * 64 + cg * 16 + lr)] = acc[rg][cg][r];
  } else {
    const int nr = n0 >> 10;
#pragma unroll
    for (int rg = 0; rg < 8; ++rg)
#pragma unroll
      for (int cg = 0; cg < 4; ++cg)
#pragma unroll
        for (int r = 0; r < 4; ++r) {
          int row = m0 + wm * 128 + rg * 16 + or0 + r;
          int col = (n0 & 1023) + wn * 64 + cg * 16 + lr;
          float x = acc[rg][cg][r];
          if (nr == 0) {
            x += bq[col];
            unsigned short h = f2bf(x);
            qh[(size_t)row * 1024 + col] = h;
            ql[(size_t)row * 1024 + col] = f2bf(x - bf2f(h));
          } else if (nr == 1) {
            x += bk[col];
            unsigned short h = f2bf(x);
            kh[(size_t)row * 1024 + col] = h;
            kl[(size_t)row * 1024 + col] = f2bf(x - bf2f(h));
          } else {
            x += bv[col];
            vT[(size_t)col * 8192 + row] = f2bf(x);
          }
        }
  }
}

// ---------- row softmax: fp32 [4096] -> bf16 probs (in-place, pld stride) ----
__global__ __launch_bounds__(256) void softmax_rows_kernel(
    const float* Sm, unsigned short* P, int ncol, int pld) {
  const int t = threadIdx.x;
  const float* srow = Sm + (size_t)blockIdx.x * ncol;
  float4 v[4];
  float m = -3.4e38f;
#pragma unroll
  for (int i = 0; i < 4; ++i) {
    v[i] = ((const float4*)srow)[t + 256 * i];
    m = fmaxf(m, fmaxf(fmaxf(v[i].x, v[i].y), fmaxf(v[i].z, v[i].w)));
  }
#pragma unroll
  for (int off = 32; off >= 1; off >>= 1) m = fmaxf(m, __shfl_down(m, off));
  __shared__ float redm[4];
  if ((t & 63) == 0) redm[t >> 6] = m;
  __syncthreads();
  m = fmaxf(fmaxf(redm[0], redm[1]), fmaxf(redm[2], redm[3]));
  float s = 0.f;
#pragma unroll
  for (int i = 0; i < 4; ++i) {
    v[i].x = __expf(v[i].x - m);
    v[i].y = __expf(v[i].y - m);
    v[i].z = __expf(v[i].z - m);
    v[i].w = __expf(v[i].w - m);
    s += v[i].x + v[i].y + v[i].z + v[i].w;
  }
#pragma unroll
  for (int off = 32; off >= 1; off >>= 1) s += __shfl_down(s, off);
  __shared__ float reds[4];
  if ((t & 63) == 0) reds[t >> 6] = s;
  __syncthreads();
  s = reds[0] + reds[1] + reds[2] + reds[3];
  float inv = 1.f / s;
  unsigned short* prow = P + (size_t)blockIdx.x * pld;
#pragma unroll
  for (int i = 0; i < 4; ++i) {
    ushort4 o = make_ushort4(f2bf(v[i].x * inv), f2bf(v[i].y * inv),
                             f2bf(v[i].z * inv), f2bf(v[i].w * inv));
    ((ushort4*)prow)[t + 256 * i] = o;
  }
}

extern "C" void kernel_launch(void* const* d_in, const int* in_sizes, int n_in,
                              void* d_out, int out_size, void* d_ws, size_t ws_size,
                              hipStream_t stream) {
  const float* hs = (const float*)d_in[0];
  const float* Wq = (const float*)d_in[1];
  const float* bq = (const float*)d_in[2];
  const float* Wk = (const float*)d_in[3];
  const float* bk = (const float*)d_in[4];
  const float* Wv = (const float*)d_in[5];
  const float* bv = (const float*)d_in[6];
  float* out = (float*)d_out;

  constexpr int Ss = 4096, Hh = 1024;
  constexpr int Mm = 8192;
  char* ws = (char*)d_ws;
  const size_t MB = 1024 * 1024;

  // region A (live): qh,ql,kh,kl,vT (16MB each) = 80MB
  unsigned short* qh = (unsigned short*)(ws + 0 * MB);
  unsigned short* ql = (unsigned short*)(ws + 16 * MB);
  unsigned short* kh = (unsigned short*)(ws + 32 * MB);
  unsigned short* kl = (unsigned short*)(ws + 48 * MB);
  unsigned short* vT = (unsigned short*)(ws + 64 * MB);  // [1024][8192]
  // region B at +80MB: early = hs splits + weights; late = 64MB score slab
  char* rb = ws + 80 * MB;
  unsigned short* hs_h = (unsigned short*)(rb + 0 * MB);
  unsigned short* hs_l = (unsigned short*)(rb + 16 * MB);
  unsigned short* WhT = (unsigned short*)(rb + 32 * MB);  // [3072][1024]
  unsigned short* WlT = (unsigned short*)(rb + 38 * MB);
  float* Sf = (float*)rb;  // 64MB slab per batch (reused), P bf16 in-place

  // 1) splits
  split_pair_kernel<<<dim3(Mm * Hh / 1024), 256, 0, stream>>>(hs, hs_h, hs_l);
  transpose_split_kernel<<<dim3(32, 32), 256, 0, stream>>>(Wq, WhT, WlT, Hh, Hh);
  transpose_split_kernel<<<dim3(32, 32), 256, 0, stream>>>(
      Wk, WhT + (size_t)1024 * 1024, WlT + (size_t)1024 * 1024, Hh, Hh);
  transpose_split_kernel<<<dim3(32, 32), 256, 0, stream>>>(
      Wv, WhT + (size_t)2048 * 1024, WlT + (size_t)2048 * 1024, Hh, Hh);

  // 2) fused QKV projection: M=8192, N=3072, K=3072 (segs {h,l,h} x {Wh,Wh,Wl})
  //    grid = (Mblocks, Nblocks)
  g8_kernel<3><<<dim3(32, 12), 512, 0, stream>>>(
      hs_h, hs_l, hs_h, hs_h, WhT, WhT, WlT, WlT,
      3072, 1024, 1024, nullptr, 0, bq, bk, bv, qh, ql, kh, kl, vT);

  // 3) per batch: scores -> softmax(in-place, bf16) -> context
  for (int b = 0; b < 2; ++b) {
    const size_t tk = (size_t)b * Ss * Hh;
    // QK^T: K=3072 segs A={qh,ql,qh}, B={kh,kh,kl}
    g8_kernel<0><<<dim3(16, 16), 512, 0, stream>>>(
        qh + tk, ql + tk, qh + tk, qh + tk,
        kh + tk, kh + tk, kl + tk, kl + tk,
        3072, 1024, 1024, Sf, Ss, nullptr, nullptr, nullptr,
        nullptr, nullptr, nullptr, nullptr, nullptr);
    softmax_rows_kernel<<<dim3(Ss), 256, 0, stream>>>(
        Sf, (unsigned short*)Sf, Ss, 2 * Ss);
    // PV: A = P bf16 (ld 8192 shorts, segs +1024k), B = vT cols (ld 8192)
    const unsigned short* P0 = (const unsigned short*)Sf;
    const unsigned short* vb = vT + (size_t)b * Ss;
    g8_kernel<0><<<dim3(16, 4), 512, 0, stream>>>(
        P0, P0 + 1024, P0 + 2048, P0 + 3072,
        vb, vb + 1024, vb + 2048, vb + 3072,
        4096, 2 * Ss, Mm, out + tk, Hh, nullptr, nullptr, nullptr,
        nullptr, nullptr, nullptr, nullptr, nullptr);
  }
}

// Round 6
// 621.318 us; speedup vs baseline: 1.2426x; 1.2426x over previous
//
#include <hip/hip_runtime.h>
#include <stdint.h>

typedef __attribute__((ext_vector_type(8))) short short8;
typedef __attribute__((ext_vector_type(8))) _Float16 half8;
typedef __attribute__((ext_vector_type(4))) float f32x4;

__device__ __forceinline__ unsigned short f2bf(float x) {
  unsigned int u = __float_as_uint(x);
  u += 0x7fffu + ((u >> 16) & 1u);
  return (unsigned short)(u >> 16);
}
__device__ __forceinline__ float bf2f(unsigned short h) {
  return __uint_as_float(((unsigned int)h) << 16);
}
__device__ __forceinline__ unsigned short f2h(float x) {
  _Float16 h = (_Float16)x;
  return __builtin_bit_cast(unsigned short, h);
}
__device__ __forceinline__ float h2f(unsigned short u) {
  return (float)__builtin_bit_cast(_Float16, u);
}

#define GLOAD16(gsrc, ldst)                                              \
  __builtin_amdgcn_global_load_lds(                                      \
      (const __attribute__((address_space(1))) void*)(gsrc),             \
      (__attribute__((address_space(3))) void*)(ldst), 16, 0, 0)

#define VM(N) asm volatile("s_waitcnt vmcnt(" #N ")" ::: "memory")
#define BARSYNC __builtin_amdgcn_s_barrier()

// ---------- split fp32 -> (hi, lo) bf16 ----------
__global__ __launch_bounds__(256) void split_pair_kernel(
    const float* __restrict__ in, unsigned short* __restrict__ h,
    unsigned short* __restrict__ l) {
  size_t i = (size_t)blockIdx.x * 256 + threadIdx.x;
  float4 v = ((const float4*)in)[i];
  unsigned short h0 = f2bf(v.x), h1 = f2bf(v.y), h2 = f2bf(v.z), h3 = f2bf(v.w);
  ((ushort4*)h)[i] = make_ushort4(h0, h1, h2, h3);
  ((ushort4*)l)[i] = make_ushort4(f2bf(v.x - bf2f(h0)), f2bf(v.y - bf2f(h1)),
                                  f2bf(v.z - bf2f(h2)), f2bf(v.w - bf2f(h3)));
}

// ---------- transpose W [K][N] fp32 -> hi/lo bf16 [N][K] ----------
__global__ __launch_bounds__(256) void transpose_split_kernel(
    const float* __restrict__ W, unsigned short* __restrict__ hT,
    unsigned short* __restrict__ lT, int Kd, int Nd) {
  __shared__ float tile[32][33];
  int r = threadIdx.x >> 3;
  int c = (threadIdx.x & 7) * 4;
  int k0 = blockIdx.y * 32, n0 = blockIdx.x * 32;
  float4 v = *(const float4*)&W[(size_t)(k0 + r) * Nd + n0 + c];
  tile[r][c] = v.x; tile[r][c + 1] = v.y; tile[r][c + 2] = v.z; tile[r][c + 3] = v.w;
  __syncthreads();
  float x0 = tile[c + 0][r], x1 = tile[c + 1][r], x2 = tile[c + 2][r], x3 = tile[c + 3][r];
  unsigned short h0 = f2bf(x0), h1 = f2bf(x1), h2 = f2bf(x2), h3 = f2bf(x3);
  size_t o = (size_t)(n0 + r) * Kd + k0 + c;
  *(ushort4*)&hT[o] = make_ushort4(h0, h1, h2, h3);
  *(ushort4*)&lT[o] = make_ushort4(f2bf(x0 - bf2f(h0)), f2bf(x1 - bf2f(h1)),
                                   f2bf(x2 - bf2f(h2)), f2bf(x3 - bf2f(h3)));
}

// =====================================================================
// R1-verified pipelined 3-term split-bf16 NT GEMM (256x128 tile, BK=32,
// 8 waves, tri-buffer 144KB, fragment-linear LDS, gload_lds, VM(6)).
// OMODE: 0 = fp32 out; 1 = f16 hi/lo pair out; 2 = bf16 transposed out.
// =====================================================================
template <int OMODE>
__global__ __launch_bounds__(512, 2) void gemm3_kernel(
    const unsigned short* __restrict__ Ah, const unsigned short* __restrict__ Al,
    const unsigned short* __restrict__ Bh, const unsigned short* __restrict__ Bl,
    const float* __restrict__ bias, void* __restrict__ out0,
    void* __restrict__ out1, int K, int lda, int ldb, int ldo) {
  __shared__ __align__(16) char smem[3 * 48 * 1024];

  const int t = threadIdx.x;
  const int wid = t >> 6;
  const int lane = t & 63;
  const int waveM = wid >> 2;
  const int waveN = wid & 3;
  const int lr0 = lane & 15;
  const int lk0 = (lane >> 4) * 8;
  const int m0 = blockIdx.y * 256;
  const int n0 = blockIdx.x * 128;

  const unsigned short* slot_src[6];
#pragma unroll
  for (int s = 0; s < 6; ++s) {
    int si = 6 * wid + s;
    const unsigned short* base;
    size_t roff;
    if (si < 16)      { base = Ah; roff = (size_t)(m0 + si * 16 + lr0) * lda; }
    else if (si < 32) { base = Al; roff = (size_t)(m0 + (si - 16) * 16 + lr0) * lda; }
    else if (si < 40) { base = Bh; roff = (size_t)(n0 + (si - 32) * 16 + lr0) * ldb; }
    else              { base = Bl; roff = (size_t)(n0 + (si - 40) * 16 + lr0) * ldb; }
    slot_src[s] = base + roff + lk0;
  }

  const int NTILES = K >> 5;
  f32x4 acc[8][2] = {};

#pragma unroll
  for (int tt = 0; tt < 2; ++tt)
#pragma unroll
    for (int s = 0; s < 6; ++s)
      GLOAD16(slot_src[s] + (size_t)tt * 32,
              smem + tt * 49152 + (6 * wid + s) * 1024);
  VM(6);
  BARSYNC;
  __builtin_amdgcn_sched_barrier(0);

  for (int tile = 0; tile < NTILES; ++tile) {
    const int cur = tile % 3;
    const int nxt = (tile + 2) % 3;
    const bool do_stage = (tile + 2) < NTILES;
    const char* cb = smem + cur * 49152;
    char* nb = smem + nxt * 49152;
    short8 b0f[2], b1f[2];
#pragma unroll
    for (int p = 0; p < 4; ++p) {
      short8 a0f[2], a1f[2];
#pragma unroll
      for (int i = 0; i < 2; ++i) {
        int mg = waveM * 8 + 2 * p + i;
        a0f[i] = *(const short8*)(cb + mg * 1024 + lane * 16);
        a1f[i] = *(const short8*)(cb + (16 + mg) * 1024 + lane * 16);
      }
      if (p == 0) {
#pragma unroll
        for (int j = 0; j < 2; ++j) {
          int ng = waveN * 2 + j;
          b0f[j] = *(const short8*)(cb + (32 + ng) * 1024 + lane * 16);
          b1f[j] = *(const short8*)(cb + (40 + ng) * 1024 + lane * 16);
        }
      }
      if (do_stage && p < 3) {
#pragma unroll
        for (int s = 0; s < 2; ++s) {
          int slot = 2 * p + s;
          GLOAD16(slot_src[slot] + (size_t)(tile + 2) * 32,
                  nb + (6 * wid + slot) * 1024);
        }
      }
      __builtin_amdgcn_s_setprio(1);
#pragma unroll
      for (int i = 0; i < 2; ++i)
#pragma unroll
        for (int j = 0; j < 2; ++j) {
          f32x4 c = acc[2 * p + i][j];
          c = __builtin_amdgcn_mfma_f32_16x16x32_bf16(a0f[i], b0f[j], c, 0, 0, 0);
          c = __builtin_amdgcn_mfma_f32_16x16x32_bf16(a0f[i], b1f[j], c, 0, 0, 0);
          c = __builtin_amdgcn_mfma_f32_16x16x32_bf16(a1f[i], b0f[j], c, 0, 0, 0);
          acc[2 * p + i][j] = c;
        }
      __builtin_amdgcn_s_setprio(0);
      if (p < 3) __builtin_amdgcn_s_barrier();
    }
    if (tile + 1 < NTILES) {
      if (do_stage) VM(6); else VM(0);
      BARSYNC;
      __builtin_amdgcn_sched_barrier(0);
    }
  }

  const int or0 = (lane >> 4) * 4;
#pragma unroll
  for (int mm = 0; mm < 8; ++mm)
#pragma unroll
    for (int j = 0; j < 2; ++j)
#pragma unroll
      for (int r = 0; r < 4; ++r) {
        int row = m0 + waveM * 128 + mm * 16 + or0 + r;
        int col = n0 + waveN * 32 + j * 16 + lr0;
        float x = acc[mm][j][r];
        if (bias) x += bias[col];
        if constexpr (OMODE == 0) {
          ((float*)out0)[(size_t)row * ldo + col] = x;
        } else if constexpr (OMODE == 1) {
          unsigned short h = f2h(x);
          ((unsigned short*)out0)[(size_t)row * ldo + col] = h;
          ((unsigned short*)out1)[(size_t)row * ldo + col] = f2h(x - h2f(h));
        } else {
          ((unsigned short*)out0)[(size_t)col * ldo + row] = f2bf(x);
        }
      }
}

// =====================================================================
// f16 2-term QK^T: C = (Qh+Ql) * Kh^T. Same verified 4-phase tri-buffer
// structure; per K-step buffer [Ah:16][Al:16][Bh:8] = 40KB (tri 120KB),
// 5 slots/wave, VM(5). 8 MFMA (f16) per phase.
// =====================================================================
__global__ __launch_bounds__(512, 2) void qk2_kernel(
    const unsigned short* __restrict__ Ah, const unsigned short* __restrict__ Al,
    const unsigned short* __restrict__ Bh, float* __restrict__ out,
    int K, int lda, int ldb, int ldo) {
  __shared__ __align__(16) char smem[3 * 40 * 1024];

  const int t = threadIdx.x;
  const int wid = t >> 6;
  const int lane = t & 63;
  const int waveM = wid >> 2;
  const int waveN = wid & 3;
  const int lr0 = lane & 15;
  const int lk0 = (lane >> 4) * 8;
  const int m0 = blockIdx.y * 256;
  const int n0 = blockIdx.x * 128;

  const unsigned short* slot_src[5];
#pragma unroll
  for (int s = 0; s < 5; ++s) {
    int si = 5 * wid + s;
    const unsigned short* base;
    size_t roff;
    if (si < 16)      { base = Ah; roff = (size_t)(m0 + si * 16 + lr0) * lda; }
    else if (si < 32) { base = Al; roff = (size_t)(m0 + (si - 16) * 16 + lr0) * lda; }
    else              { base = Bh; roff = (size_t)(n0 + (si - 32) * 16 + lr0) * ldb; }
    slot_src[s] = base + roff + lk0;
  }

  const int NTILES = K >> 5;
  f32x4 acc[8][2] = {};

#pragma unroll
  for (int tt = 0; tt < 2; ++tt)
#pragma unroll
    for (int s = 0; s < 5; ++s)
      GLOAD16(slot_src[s] + (size_t)tt * 32,
              smem + tt * 40960 + (5 * wid + s) * 1024);
  VM(5);
  BARSYNC;
  __builtin_amdgcn_sched_barrier(0);

  for (int tile = 0; tile < NTILES; ++tile) {
    const int cur = tile % 3;
    const int nxt = (tile + 2) % 3;
    const bool do_stage = (tile + 2) < NTILES;
    const char* cb = smem + cur * 40960;
    char* nb = smem + nxt * 40960;
    half8 bf[2];
#pragma unroll
    for (int p = 0; p < 4; ++p) {
      half8 ahf[2], alf[2];
#pragma unroll
      for (int i = 0; i < 2; ++i) {
        int mg = waveM * 8 + 2 * p + i;
        ahf[i] = *(const half8*)(cb + mg * 1024 + lane * 16);
        alf[i] = *(const half8*)(cb + (16 + mg) * 1024 + lane * 16);
      }
      if (p == 0) {
#pragma unroll
        for (int j = 0; j < 2; ++j) {
          int ng = waveN * 2 + j;
          bf[j] = *(const half8*)(cb + (32 + ng) * 1024 + lane * 16);
        }
      }
      if (do_stage) {
        if (p == 0) {
          GLOAD16(slot_src[0] + (size_t)(tile + 2) * 32, nb + (5 * wid + 0) * 1024);
          GLOAD16(slot_src[1] + (size_t)(tile + 2) * 32, nb + (5 * wid + 1) * 1024);
        } else {
          const int slot = p + 1;  // p=1->2, p=2->3, p=3->4
          GLOAD16(slot_src[slot] + (size_t)(tile + 2) * 32,
                  nb + (5 * wid + slot) * 1024);
        }
      }
      __builtin_amdgcn_s_setprio(1);
#pragma unroll
      for (int i = 0; i < 2; ++i)
#pragma unroll
        for (int j = 0; j < 2; ++j) {
          f32x4 c = acc[2 * p + i][j];
          c = __builtin_amdgcn_mfma_f32_16x16x32_f16(ahf[i], bf[j], c, 0, 0, 0);
          c = __builtin_amdgcn_mfma_f32_16x16x32_f16(alf[i], bf[j], c, 0, 0, 0);
          acc[2 * p + i][j] = c;
        }
      __builtin_amdgcn_s_setprio(0);
      if (p < 3) __builtin_amdgcn_s_barrier();
    }
    if (tile + 1 < NTILES) {
      if (do_stage) VM(5); else VM(0);
      BARSYNC;
      __builtin_amdgcn_sched_barrier(0);
    }
  }

  const int or0 = (lane >> 4) * 4;
#pragma unroll
  for (int mm = 0; mm < 8; ++mm)
#pragma unroll
    for (int j = 0; j < 2; ++j)
#pragma unroll
      for (int r = 0; r < 4; ++r)
        out[(size_t)(m0 + waveM * 128 + mm * 16 + or0 + r) * ldo +
            (n0 + waveN * 32 + j * 16 + lr0)] = acc[mm][j][r];
}

// ---------- old 128x128 NT GEMM (PV: NT=1, fp32 out) ----------
constexpr int BM = 128, BN = 128, BKT = 32, RS = 56;

template <int NT, int OMODE>
__global__ __launch_bounds__(256) void gemm_nt_kernel(
    const unsigned short* __restrict__ Ah, const unsigned short* __restrict__ Al,
    const unsigned short* __restrict__ Bh, const unsigned short* __restrict__ Bl,
    const float* __restrict__ bias, void* __restrict__ out0,
    void* __restrict__ out1, int K, int lda, int ldb, int ldo) {
  __shared__ unsigned short sAh[BM * RS];
  __shared__ unsigned short sBh[BN * RS];
  __shared__ unsigned short sAl[NT == 3 ? BM * RS : 8];
  __shared__ unsigned short sBl[NT == 3 ? BN * RS : 8];

  const int t = threadIdx.x;
  const int m0 = blockIdx.y * BM;
  const int n0 = blockIdx.x * BN;
  const int wid = t >> 6;
  const int lane = t & 63;
  const int wm = (wid >> 1) * 64;
  const int wn = (wid & 1) * 64;
  const int lr = lane & 15;
  const int lk = (lane >> 4) * 8;
  const int sr = t >> 2;
  const int sc = (t & 3) * 8;

  f32x4 acc[4][4] = {};

  for (int k0 = 0; k0 < K; k0 += BKT) {
#pragma unroll
    for (int p = 0; p < 2; ++p) {
      int row = p * 64 + sr;
      *(uint4*)&sAh[row * RS + sc] = *(const uint4*)&Ah[(size_t)(m0 + row) * lda + k0 + sc];
      *(uint4*)&sBh[row * RS + sc] = *(const uint4*)&Bh[(size_t)(n0 + row) * ldb + k0 + sc];
      if constexpr (NT == 3) {
        *(uint4*)&sAl[row * RS + sc] = *(const uint4*)&Al[(size_t)(m0 + row) * lda + k0 + sc];
        *(uint4*)&sBl[row * RS + sc] = *(const uint4*)&Bl[(size_t)(n0 + row) * ldb + k0 + sc];
      }
    }
    __syncthreads();
    short8 ah[4], bh[4], al[4], bl[4];
#pragma unroll
    for (int m = 0; m < 4; ++m) {
      ah[m] = *(const short8*)&sAh[(wm + m * 16 + lr) * RS + lk];
      bh[m] = *(const short8*)&sBh[(wn + m * 16 + lr) * RS + lk];
      if constexpr (NT == 3) {
        al[m] = *(const short8*)&sAl[(wm + m * 16 + lr) * RS + lk];
        bl[m] = *(const short8*)&sBl[(wn + m * 16 + lr) * RS + lk];
      }
    }
#pragma unroll
    for (int m = 0; m < 4; ++m)
#pragma unroll
      for (int n = 0; n < 4; ++n) {
        acc[m][n] = __builtin_amdgcn_mfma_f32_16x16x32_bf16(ah[m], bh[n], acc[m][n], 0, 0, 0);
        if constexpr (NT == 3) {
          acc[m][n] = __builtin_amdgcn_mfma_f32_16x16x32_bf16(ah[m], bl[n], acc[m][n], 0, 0, 0);
          acc[m][n] = __builtin_amdgcn_mfma_f32_16x16x32_bf16(al[m], bh[n], acc[m][n], 0, 0, 0);
        }
      }
    __syncthreads();
  }

  const int or0 = (lane >> 4) * 4;
#pragma unroll
  for (int m = 0; m < 4; ++m)
#pragma unroll
    for (int n = 0; n < 4; ++n)
#pragma unroll
      for (int r = 0; r < 4; ++r) {
        int row = m0 + wm + m * 16 + or0 + r;
        int col = n0 + wn + n * 16 + lr;
        float x = acc[m][n][r];
        if (bias) x += bias[col];
        if constexpr (OMODE == 0) {
          ((float*)out0)[(size_t)row * ldo + col] = x;
        } else if constexpr (OMODE == 1) {
          unsigned short h = f2bf(x);
          ((unsigned short*)out0)[(size_t)row * ldo + col] = h;
          ((unsigned short*)out1)[(size_t)row * ldo + col] = f2bf(x - bf2f(h));
        } else {
          ((unsigned short*)out0)[(size_t)col * ldo + row] = f2bf(x);
        }
      }
}

// ---------- row softmax: fp32 [4096] -> bf16 probs ----------
__global__ __launch_bounds__(256) void softmax_rows_kernel(
    const float* __restrict__ Sm, unsigned short* __restrict__ P, int ncol) {
  const int t = threadIdx.x;
  const float* srow = Sm + (size_t)blockIdx.x * ncol;
  float4 v[4];
  float m = -3.4e38f;
#pragma unroll
  for (int i = 0; i < 4; ++i) {
    v[i] = ((const float4*)srow)[t + 256 * i];
    m = fmaxf(m, fmaxf(fmaxf(v[i].x, v[i].y), fmaxf(v[i].z, v[i].w)));
  }
#pragma unroll
  for (int off = 32; off >= 1; off >>= 1) m = fmaxf(m, __shfl_down(m, off));
  __shared__ float redm[4];
  if ((t & 63) == 0) redm[t >> 6] = m;
  __syncthreads();
  m = fmaxf(fmaxf(redm[0], redm[1]), fmaxf(redm[2], redm[3]));
  float s = 0.f;
#pragma unroll
  for (int i = 0; i < 4; ++i) {
    v[i].x = __expf(v[i].x - m);
    v[i].y = __expf(v[i].y - m);
    v[i].z = __expf(v[i].z - m);
    v[i].w = __expf(v[i].w - m);
    s += v[i].x + v[i].y + v[i].z + v[i].w;
  }
#pragma unroll
  for (int off = 32; off >= 1; off >>= 1) s += __shfl_down(s, off);
  __shared__ float reds[4];
  if ((t & 63) == 0) reds[t >> 6] = s;
  __syncthreads();
  s = reds[0] + reds[1] + reds[2] + reds[3];
  float inv = 1.f / s;
  unsigned short* prow = P + (size_t)blockIdx.x * ncol;
#pragma unroll
  for (int i = 0; i < 4; ++i) {
    ushort4 o = make_ushort4(f2bf(v[i].x * inv), f2bf(v[i].y * inv),
                             f2bf(v[i].z * inv), f2bf(v[i].w * inv));
    ((ushort4*)prow)[t + 256 * i] = o;
  }
}

extern "C" void kernel_launch(void* const* d_in, const int* in_sizes, int n_in,
                              void* d_out, int out_size, void* d_ws, size_t ws_size,
                              hipStream_t stream) {
  const float* hs = (const float*)d_in[0];
  const float* Wq = (const float*)d_in[1];
  const float* bq = (const float*)d_in[2];
  const float* Wk = (const float*)d_in[3];
  const float* bk = (const float*)d_in[4];
  const float* Wv = (const float*)d_in[5];
  const float* bv = (const float*)d_in[6];
  float* out = (float*)d_out;

  constexpr int Bb = 2, Ss = 4096, Hh = 1024;
  constexpr int Mm = Bb * Ss;
  char* ws = (char*)d_ws;

  const size_t szSplit = (size_t)Mm * Hh * 2;  // 16 MB
  const size_t szW = (size_t)Hh * Hh * 2;      // 2 MB
  unsigned short* hs_h = (unsigned short*)(ws + 0);
  unsigned short* hs_l = (unsigned short*)(ws + szSplit);
  unsigned short* WqhT = (unsigned short*)(ws + 2 * szSplit + 0 * szW);
  unsigned short* WqlT = (unsigned short*)(ws + 2 * szSplit + 1 * szW);
  unsigned short* WkhT = (unsigned short*)(ws + 2 * szSplit + 2 * szW);
  unsigned short* WklT = (unsigned short*)(ws + 2 * szSplit + 3 * szW);
  unsigned short* WvhT = (unsigned short*)(ws + 2 * szSplit + 4 * szW);
  unsigned short* WvlT = (unsigned short*)(ws + 2 * szSplit + 5 * szW);
  float* Sbuf = (float*)(ws + 0);
  unsigned short* Pbuf = (unsigned short*)(ws + (size_t)Ss * Ss * 4);
  char* bbase = ws + (size_t)Ss * Ss * 4 + (size_t)Ss * Ss * 2;
  unsigned short* qh = (unsigned short*)(bbase + 0 * szSplit);  // f16 bits
  unsigned short* ql = (unsigned short*)(bbase + 1 * szSplit);  // f16 bits
  unsigned short* kh = (unsigned short*)(bbase + 2 * szSplit);  // f16 bits
  unsigned short* kl = (unsigned short*)(bbase + 3 * szSplit);  // f16 bits (unused in QK^T)
  unsigned short* vT = (unsigned short*)(bbase + 4 * szSplit);  // bf16 [H][Mm]

  // 1) split inputs (bf16 hi/lo for the 3-term projections)
  split_pair_kernel<<<dim3(Mm * Hh / 1024), 256, 0, stream>>>(hs, hs_h, hs_l);
  transpose_split_kernel<<<dim3(32, 32), 256, 0, stream>>>(Wq, WqhT, WqlT, Hh, Hh);
  transpose_split_kernel<<<dim3(32, 32), 256, 0, stream>>>(Wk, WkhT, WklT, Hh, Hh);
  transpose_split_kernel<<<dim3(32, 32), 256, 0, stream>>>(Wv, WvhT, WvlT, Hh, Hh);

  // 2) projections (bf16 3-term): q,k -> f16 hi/lo pairs; v -> transposed bf16
  gemm3_kernel<1><<<dim3(Hh / 128, Mm / 256), 512, 0, stream>>>(
      hs_h, hs_l, WqhT, WqlT, bq, qh, ql, Hh, Hh, Hh, Hh);
  gemm3_kernel<1><<<dim3(Hh / 128, Mm / 256), 512, 0, stream>>>(
      hs_h, hs_l, WkhT, WklT, bk, kh, kl, Hh, Hh, Hh, Hh);
  gemm3_kernel<2><<<dim3(Hh / 128, Mm / 256), 512, 0, stream>>>(
      hs_h, hs_l, WvhT, WvlT, bv, vT, nullptr, Hh, Hh, Hh, Mm);

  // 3) per batch: scores (f16 2-term) -> softmax -> context
  for (int b = 0; b < 2; ++b) {
    const size_t tok = (size_t)b * Ss * Hh;
    qk2_kernel<<<dim3(Ss / 128, Ss / 256), 512, 0, stream>>>(
        qh + tok, ql + tok, kh + tok, Sbuf, Hh, Hh, Hh, Ss);
    softmax_rows_kernel<<<dim3(Ss), 256, 0, stream>>>(Sbuf, Pbuf, Ss);
    gemm_nt_kernel<1, 0><<<dim3(Hh / BN, Ss / BM), 256, 0, stream>>>(
        Pbuf, nullptr, vT + (size_t)b * Ss, nullptr, nullptr,
        out + tok, nullptr, Ss, Ss, Mm, Hh);
  }
}

// Round 7
// 417.345 us; speedup vs baseline: 1.8499x; 1.4887x over previous
//
#include <hip/hip_runtime.h>
#include <stdint.h>

typedef __attribute__((ext_vector_type(8))) short short8;
typedef __attribute__((ext_vector_type(8))) _Float16 half8;
typedef __attribute__((ext_vector_type(4))) float f32x4;

__device__ __forceinline__ unsigned short f2h(float x) {
  _Float16 h = (_Float16)x;
  return __builtin_bit_cast(unsigned short, h);
}
__device__ __forceinline__ float h2f(unsigned short u) {
  return (float)__builtin_bit_cast(_Float16, u);
}

#define GLOAD16(gsrc, ldst)                                              \
  __builtin_amdgcn_global_load_lds(                                      \
      (const __attribute__((address_space(1))) void*)(gsrc),             \
      (__attribute__((address_space(3))) void*)(ldst), 16, 0, 0)

#define VM(N) asm volatile("s_waitcnt vmcnt(" #N ")" ::: "memory")
#define BARSYNC __builtin_amdgcn_s_barrier()

// ---------- split fp32 -> (hi, lo) f16 ----------
__global__ __launch_bounds__(256) void split_pair_f16_kernel(
    const float* __restrict__ in, unsigned short* __restrict__ h,
    unsigned short* __restrict__ l) {
  size_t i = (size_t)blockIdx.x * 256 + threadIdx.x;
  float4 v = ((const float4*)in)[i];
  unsigned short h0 = f2h(v.x), h1 = f2h(v.y), h2 = f2h(v.z), h3 = f2h(v.w);
  ((ushort4*)h)[i] = make_ushort4(h0, h1, h2, h3);
  ((ushort4*)l)[i] = make_ushort4(f2h(v.x - h2f(h0)), f2h(v.y - h2f(h1)),
                                  f2h(v.z - h2f(h2)), f2h(v.w - h2f(h3)));
}

// ---------- transpose W [K][N] fp32 -> f16 [N][K] ----------
__global__ __launch_bounds__(256) void transpose_f16_kernel(
    const float* __restrict__ W, unsigned short* __restrict__ hT,
    int Kd, int Nd) {
  __shared__ float tile[32][33];
  int r = threadIdx.x >> 3;
  int c = (threadIdx.x & 7) * 4;
  int k0 = blockIdx.y * 32, n0 = blockIdx.x * 32;
  float4 v = *(const float4*)&W[(size_t)(k0 + r) * Nd + n0 + c];
  tile[r][c] = v.x; tile[r][c + 1] = v.y; tile[r][c + 2] = v.z; tile[r][c + 3] = v.w;
  __syncthreads();
  size_t o = (size_t)(n0 + r) * Kd + k0 + c;
  *(ushort4*)&hT[o] = make_ushort4(f2h(tile[c + 0][r]), f2h(tile[c + 1][r]),
                                   f2h(tile[c + 2][r]), f2h(tile[c + 3][r]));
}

// =====================================================================
// g2: 2-term f16 NT GEMM (proj): C = (Ah+Al)*Bh^T + bias. 256x128 tile,
// BK=32, tri-buffer 120KB, 5 slots/wave, VM(5). (R5-proven structure.)
// OM=4: f16 out [row*ldo+col]; OM=2: f16 transposed [col*ldo+row].
// =====================================================================
template <int OM>
__global__ __launch_bounds__(512, 2) void g2_kernel(
    const unsigned short* __restrict__ Ah, const unsigned short* __restrict__ Al,
    const unsigned short* __restrict__ Bh, const float* __restrict__ bias,
    unsigned short* __restrict__ out0, int K, int lda, int ldb, int ldo) {
  __shared__ __align__(16) char smem[3 * 40 * 1024];

  const int t = threadIdx.x;
  const int wid = t >> 6, lane = t & 63;
  const int waveM = wid >> 2, waveN = wid & 3;
  const int lr0 = lane & 15, lk0 = (lane >> 4) * 8;
  const int m0 = blockIdx.y * 256, n0 = blockIdx.x * 128;

  const unsigned short* slot_src[5];
#pragma unroll
  for (int s = 0; s < 5; ++s) {
    int si = 5 * wid + s;
    const unsigned short* base;
    size_t roff;
    if (si < 16)      { base = Ah; roff = (size_t)(m0 + si * 16 + lr0) * lda; }
    else if (si < 32) { base = Al; roff = (size_t)(m0 + (si - 16) * 16 + lr0) * lda; }
    else              { base = Bh; roff = (size_t)(n0 + (si - 32) * 16 + lr0) * ldb; }
    slot_src[s] = base + roff + lk0;
  }

  const int NTILES = K >> 5;
  f32x4 acc[8][2] = {};

#pragma unroll
  for (int tt = 0; tt < 2; ++tt)
#pragma unroll
    for (int s = 0; s < 5; ++s)
      GLOAD16(slot_src[s] + (size_t)tt * 32,
              smem + tt * 40960 + (5 * wid + s) * 1024);
  VM(5);
  BARSYNC;
  __builtin_amdgcn_sched_barrier(0);

  for (int tile = 0; tile < NTILES; ++tile) {
    const int cur = tile % 3;
    const int nxt = (tile + 2) % 3;
    const bool do_stage = (tile + 2) < NTILES;
    const char* cb = smem + cur * 40960;
    char* nb = smem + nxt * 40960;
    half8 bf[2];
#pragma unroll
    for (int p = 0; p < 4; ++p) {
      half8 ahf[2], alf[2];
#pragma unroll
      for (int i = 0; i < 2; ++i) {
        int mg = waveM * 8 + 2 * p + i;
        ahf[i] = *(const half8*)(cb + mg * 1024 + lane * 16);
        alf[i] = *(const half8*)(cb + (16 + mg) * 1024 + lane * 16);
      }
      if (p == 0) {
#pragma unroll
        for (int j = 0; j < 2; ++j) {
          int ng = waveN * 2 + j;
          bf[j] = *(const half8*)(cb + (32 + ng) * 1024 + lane * 16);
        }
      }
      if (do_stage) {
        if (p == 0) {
          GLOAD16(slot_src[0] + (size_t)(tile + 2) * 32, nb + (5 * wid + 0) * 1024);
          GLOAD16(slot_src[1] + (size_t)(tile + 2) * 32, nb + (5 * wid + 1) * 1024);
        } else {
          const int slot = p + 1;
          GLOAD16(slot_src[slot] + (size_t)(tile + 2) * 32,
                  nb + (5 * wid + slot) * 1024);
        }
      }
      __builtin_amdgcn_s_setprio(1);
#pragma unroll
      for (int i = 0; i < 2; ++i)
#pragma unroll
        for (int j = 0; j < 2; ++j) {
          f32x4 c = acc[2 * p + i][j];
          c = __builtin_amdgcn_mfma_f32_16x16x32_f16(ahf[i], bf[j], c, 0, 0, 0);
          c = __builtin_amdgcn_mfma_f32_16x16x32_f16(alf[i], bf[j], c, 0, 0, 0);
          acc[2 * p + i][j] = c;
        }
      __builtin_amdgcn_s_setprio(0);
      if (p < 3) __builtin_amdgcn_s_barrier();
    }
    if (tile + 1 < NTILES) {
      if (do_stage) VM(5); else VM(0);
      BARSYNC;
      __builtin_amdgcn_sched_barrier(0);
    }
  }

  const int or0 = (lane >> 4) * 4;
#pragma unroll
  for (int mm = 0; mm < 8; ++mm)
#pragma unroll
    for (int j = 0; j < 2; ++j)
#pragma unroll
      for (int r = 0; r < 4; ++r) {
        int row = m0 + waveM * 128 + mm * 16 + or0 + r;
        int col = n0 + waveN * 32 + j * 16 + lr0;
        float x = acc[mm][j][r] + bias[col];
        if constexpr (OM == 4) {
          out0[(size_t)row * ldo + col] = f2h(x);
        } else {
          out0[(size_t)col * ldo + row] = f2h(x);
        }
      }
}

// =====================================================================
// g1: 1-term f16 NT GEMM: C = A*B^T, fp32 out. 256x128 tile, BK=64,
// 48 subtiles (A-klo 0-15, A-khi 16-31, B-klo 32-39, B-khi 40-47) =
// 48KB/step, tri-buffer 144KB, 6 slots/wave, VM(6), stage 2/phase (p<3)
// -- the gemm3-proven schedule. blockIdx.z selects A/B/out strides.
// =====================================================================
__global__ __launch_bounds__(512, 2) void g1_kernel(
    const unsigned short* __restrict__ Abase, size_t Astr, int lda,
    const unsigned short* __restrict__ Bbase, size_t Bstr, int ldb,
    float* __restrict__ outF, size_t Ostr, int ldo, int K) {
  __shared__ __align__(16) char smem[3 * 48 * 1024];
  const int t = threadIdx.x, wid = t >> 6, lane = t & 63;
  const int waveM = wid >> 2, waveN = wid & 3;
  const int lr0 = lane & 15, lk0 = (lane >> 4) * 8;
  const int m0 = blockIdx.y * 256, n0 = blockIdx.x * 128;
  const unsigned short* A = Abase + (size_t)blockIdx.z * Astr;
  const unsigned short* B = Bbase + (size_t)blockIdx.z * Bstr;
  float* out = outF + (size_t)blockIdx.z * Ostr;

  const unsigned short* slot_src[6];
#pragma unroll
  for (int s = 0; s < 6; ++s) {
    int si = 6 * wid + s;
    const unsigned short* p;
    if (si < 16)      p = A + (size_t)(m0 + si * 16 + lr0) * lda + lk0;
    else if (si < 32) p = A + (size_t)(m0 + (si - 16) * 16 + lr0) * lda + 32 + lk0;
    else if (si < 40) p = B + (size_t)(n0 + (si - 32) * 16 + lr0) * ldb + lk0;
    else              p = B + (size_t)(n0 + (si - 40) * 16 + lr0) * ldb + 32 + lk0;
    slot_src[s] = p;
  }

  const int NTILES = K >> 6;
  f32x4 acc[8][2] = {};

#pragma unroll
  for (int tt = 0; tt < 2; ++tt)
#pragma unroll
    for (int s = 0; s < 6; ++s)
      GLOAD16(slot_src[s] + (size_t)tt * 64,
              smem + tt * 49152 + (6 * wid + s) * 1024);
  VM(6);
  BARSYNC;
  __builtin_amdgcn_sched_barrier(0);

  for (int tile = 0; tile < NTILES; ++tile) {
    const int cur = tile % 3, nxt = (tile + 2) % 3;
    const bool do_stage = (tile + 2) < NTILES;
    const char* cb = smem + cur * 49152;
    char* nb = smem + nxt * 49152;
    half8 blo[2], bhi[2];
#pragma unroll
    for (int p = 0; p < 4; ++p) {
      half8 alo[2], ahi[2];
#pragma unroll
      for (int i = 0; i < 2; ++i) {
        int mg = waveM * 8 + 2 * p + i;
        alo[i] = *(const half8*)(cb + mg * 1024 + lane * 16);
        ahi[i] = *(const half8*)(cb + (16 + mg) * 1024 + lane * 16);
      }
      if (p == 0) {
#pragma unroll
        for (int j = 0; j < 2; ++j) {
          int ng = waveN * 2 + j;
          blo[j] = *(const half8*)(cb + (32 + ng) * 1024 + lane * 16);
          bhi[j] = *(const half8*)(cb + (40 + ng) * 1024 + lane * 16);
        }
      }
      if (do_stage && p < 3) {
#pragma unroll
        for (int s = 0; s < 2; ++s) {
          int slot = 2 * p + s;
          GLOAD16(slot_src[slot] + (size_t)(tile + 2) * 64,
                  nb + (6 * wid + slot) * 1024);
        }
      }
      __builtin_amdgcn_s_setprio(1);
#pragma unroll
      for (int i = 0; i < 2; ++i)
#pragma unroll
        for (int j = 0; j < 2; ++j) {
          f32x4 c = acc[2 * p + i][j];
          c = __builtin_amdgcn_mfma_f32_16x16x32_f16(alo[i], blo[j], c, 0, 0, 0);
          c = __builtin_amdgcn_mfma_f32_16x16x32_f16(ahi[i], bhi[j], c, 0, 0, 0);
          acc[2 * p + i][j] = c;
        }
      __builtin_amdgcn_s_setprio(0);
      if (p < 3) __builtin_amdgcn_s_barrier();
    }
    if (tile + 1 < NTILES) {
      if (do_stage) VM(6); else VM(0);
      BARSYNC;
      __builtin_amdgcn_sched_barrier(0);
    }
  }

  const int or0 = (lane >> 4) * 4;
#pragma unroll
  for (int mm = 0; mm < 8; ++mm)
#pragma unroll
    for (int j = 0; j < 2; ++j)
#pragma unroll
      for (int r = 0; r < 4; ++r)
        out[(size_t)(m0 + waveM * 128 + mm * 16 + or0 + r) * ldo +
            (n0 + waveN * 32 + j * 16 + lr0)] = acc[mm][j][r];
}

// ---------- row softmax: fp32 [4096] -> f16 probs (in-place capable) ----------
__global__ __launch_bounds__(256) void softmax_rows_kernel(
    const float* Sm, unsigned short* P, int ncol, int pld) {
  const int t = threadIdx.x;
  const float* srow = Sm + (size_t)blockIdx.x * ncol;
  float4 v[4];
  float m = -3.4e38f;
#pragma unroll
  for (int i = 0; i < 4; ++i) {
    v[i] = ((const float4*)srow)[t + 256 * i];
    m = fmaxf(m, fmaxf(fmaxf(v[i].x, v[i].y), fmaxf(v[i].z, v[i].w)));
  }
#pragma unroll
  for (int off = 32; off >= 1; off >>= 1) m = fmaxf(m, __shfl_down(m, off));
  __shared__ float redm[4];
  if ((t & 63) == 0) redm[t >> 6] = m;
  __syncthreads();
  m = fmaxf(fmaxf(redm[0], redm[1]), fmaxf(redm[2], redm[3]));
  float s = 0.f;
#pragma unroll
  for (int i = 0; i < 4; ++i) {
    v[i].x = __expf(v[i].x - m);
    v[i].y = __expf(v[i].y - m);
    v[i].z = __expf(v[i].z - m);
    v[i].w = __expf(v[i].w - m);
    s += v[i].x + v[i].y + v[i].z + v[i].w;
  }
#pragma unroll
  for (int off = 32; off >= 1; off >>= 1) s += __shfl_down(s, off);
  __shared__ float reds[4];
  if ((t & 63) == 0) reds[t >> 6] = s;
  __syncthreads();
  s = reds[0] + reds[1] + reds[2] + reds[3];
  float inv = 1.f / s;
  unsigned short* prow = P + (size_t)blockIdx.x * pld;
#pragma unroll
  for (int i = 0; i < 4; ++i) {
    ushort4 o = make_ushort4(f2h(v[i].x * inv), f2h(v[i].y * inv),
                             f2h(v[i].z * inv), f2h(v[i].w * inv));
    ((ushort4*)prow)[t + 256 * i] = o;
  }
}

extern "C" void kernel_launch(void* const* d_in, const int* in_sizes, int n_in,
                              void* d_out, int out_size, void* d_ws, size_t ws_size,
                              hipStream_t stream) {
  const float* hs = (const float*)d_in[0];
  const float* Wq = (const float*)d_in[1];
  const float* bq = (const float*)d_in[2];
  const float* Wk = (const float*)d_in[3];
  const float* bk = (const float*)d_in[4];
  const float* Wv = (const float*)d_in[5];
  const float* bv = (const float*)d_in[6];
  float* out = (float*)d_out;

  constexpr int Ss = 4096, Hh = 1024;
  constexpr int Mm = 8192;
  constexpr size_t TOK = (size_t)Ss * Hh;      // 4 Mi elems (per-batch q/k)
  char* ws = (char*)d_ws;
  const size_t MB = 1024 * 1024;

  // live region [0,48MB): qh, kh (f16 [8192][1024]); vT (f16 [1024][8192])
  unsigned short* qh = (unsigned short*)(ws + 0 * MB);
  unsigned short* kh = (unsigned short*)(ws + 16 * MB);
  unsigned short* vT = (unsigned short*)(ws + 32 * MB);
  // region at +48MB: early = hs f16 splits (32MB) + W f16 (6MB);
  // late = S slabs (big: 2x64MB in-place P; small: 64MB S + 32MB P)
  char* rb = ws + 48 * MB;
  unsigned short* hs_h = (unsigned short*)(rb + 0 * MB);
  unsigned short* hs_l = (unsigned short*)(rb + 16 * MB);
  unsigned short* Wqh = (unsigned short*)(rb + 32 * MB);
  unsigned short* Wkh = (unsigned short*)(rb + 34 * MB);
  unsigned short* Wvh = (unsigned short*)(rb + 36 * MB);
  float* Sf = (float*)rb;

  const bool big = ws_size >= (size_t)176 * MB;

  // 1) splits
  split_pair_f16_kernel<<<dim3(Mm * Hh / 1024), 256, 0, stream>>>(hs, hs_h, hs_l);
  transpose_f16_kernel<<<dim3(32, 32), 256, 0, stream>>>(Wq, Wqh, Hh, Hh);
  transpose_f16_kernel<<<dim3(32, 32), 256, 0, stream>>>(Wk, Wkh, Hh, Hh);
  transpose_f16_kernel<<<dim3(32, 32), 256, 0, stream>>>(Wv, Wvh, Hh, Hh);

  // 2) projections (2-term f16): q,k -> f16; v -> f16 transposed [H][Mm]
  g2_kernel<4><<<dim3(8, 32), 512, 0, stream>>>(hs_h, hs_l, Wqh, bq, qh, Hh, Hh, Hh, Hh);
  g2_kernel<4><<<dim3(8, 32), 512, 0, stream>>>(hs_h, hs_l, Wkh, bk, kh, Hh, Hh, Hh, Hh);
  g2_kernel<2><<<dim3(8, 32), 512, 0, stream>>>(hs_h, hs_l, Wvh, bv, vT, Hh, Hh, Hh, Mm);

  if (big) {
    // 3) QK^T both batches -> S slabs (fp32, ld 4096); rows 0..8191 contiguous
    g1_kernel<<<dim3(32, 16, 2), 512, 0, stream>>>(
        qh, TOK, Hh, kh, TOK, Hh, Sf, (size_t)Ss * Ss, Ss, Hh);
    // 4) softmax all 8192 rows, in-place strided P f16 (pld = 8192 shorts)
    softmax_rows_kernel<<<dim3(2 * Ss), 256, 0, stream>>>(
        Sf, (unsigned short*)Sf, Ss, 2 * Ss);
    // 5) PV both batches: A = P (lda 8192, slab stride 32M shorts), B = vT cols
    g1_kernel<<<dim3(8, 16, 2), 512, 0, stream>>>(
        (const unsigned short*)Sf, (size_t)Ss * 2 * Ss, 2 * Ss,
        vT, (size_t)Ss, Mm, out, TOK, Hh, Ss);
  } else {
    float* Sb = (float*)rb;                           // 64MB S
    unsigned short* Pb = (unsigned short*)(rb + 64 * MB);  // 32MB P f16 compact
    for (int b = 0; b < 2; ++b) {
      g1_kernel<<<dim3(32, 16, 1), 512, 0, stream>>>(
          qh + b * TOK, 0, Hh, kh + b * TOK, 0, Hh, Sb, 0, Ss, Hh);
      softmax_rows_kernel<<<dim3(Ss), 256, 0, stream>>>(Sb, Pb, Ss, Ss);
      g1_kernel<<<dim3(8, 16, 1), 512, 0, stream>>>(
          Pb, 0, Ss, vT + (size_t)b * Ss, 0, Mm, out + b * TOK, 0, Hh, Ss);
    }
  }
}